// Round 4
// baseline (586.870 us; speedup 1.0000x reference)
//
#include <hip/hip_runtime.h>

#define D 128
#define BN_EPS 1e-5f
#define NBUCK 256     // coarse buckets, dst>>9 (196 used at N=100K)
#define BSHIFT 9
#define CHB 4096      // edges per block, partition scatter
#define CHC 4096      // edges per block, fine fill

using short8 = __attribute__((ext_vector_type(8))) short;
using floatx4 = __attribute__((ext_vector_type(4))) float;

__device__ inline unsigned short f2bf(float f) {
    unsigned u = __float_as_uint(f);
    u += 0x7fff + ((u >> 16) & 1);  // RNE
    return (unsigned short)(u >> 16);
}
__device__ inline float bf2f(unsigned short s) {
    return __uint_as_float(((unsigned)s) << 16);
}

// ---------- pA: global bucket histogram (LDS-aggregated) + degree atomics ----------
__global__ __launch_bounds__(256) void pA_kernel(const int* __restrict__ dst,
                                                 int* __restrict__ bucketTot,
                                                 int* __restrict__ deg, int E) {
    __shared__ int lh[NBUCK];
    int tid = threadIdx.x;
    lh[tid] = 0;
    __syncthreads();
    for (int i = blockIdx.x * 256 + tid; i < E; i += gridDim.x * 256) {
        int d = dst[i];
        atomicAdd(&lh[d >> BSHIFT], 1);
        atomicAdd(&deg[d], 1);
    }
    __syncthreads();
    if (lh[tid]) atomicAdd(&bucketTot[tid], lh[tid]);
}

// ---------- tiny scan: bucketTot -> bucketCur (exclusive bases) ----------
__global__ __launch_bounds__(256) void tinyScan_kernel(const int* __restrict__ bucketTot,
                                                       int* __restrict__ bucketCur) {
    __shared__ int a[NBUCK];
    int t = threadIdx.x;
    int orig = bucketTot[t];
    a[t] = orig;
    __syncthreads();
    for (int d = 1; d < NBUCK; d <<= 1) {
        int v = (t >= d) ? a[t - d] : 0;
        __syncthreads();
        a[t] += v;
        __syncthreads();
    }
    bucketCur[t] = a[t] - orig;  // exclusive
}

// ---------- pB: reservation-based partition into bucket order ----------
__global__ __launch_bounds__(256) void pB_kernel(const int* __restrict__ src,
                                                 const int* __restrict__ dst,
                                                 int* __restrict__ bucketCur,
                                                 int2* __restrict__ pairs, int E) {
    __shared__ int2 se[CHB];
    __shared__ int lh[NBUCK];
    __shared__ int lcur[NBUCK];
    int tid = threadIdx.x;
    lh[tid] = 0;
    __syncthreads();
    int base = blockIdx.x * CHB;
    int lim = min(CHB, E - base);
    for (int i = tid; i < lim; i += 256) {
        int s = src[base + i], d = dst[base + i];
        se[i] = make_int2(s, d);
        atomicAdd(&lh[d >> BSHIFT], 1);
    }
    __syncthreads();
    int c = lh[tid];
    lcur[tid] = c ? atomicAdd(&bucketCur[tid], c) : 0;
    __syncthreads();
    for (int i = tid; i < lim; i += 256) {
        int2 p = se[i];
        int pos = atomicAdd(&lcur[p.y >> BSHIFT], 1);
        pairs[pos] = p;
    }
}

// ---------- fallback degree (random atomics) ----------
__global__ void deg_kernel(const int* __restrict__ dst, int* __restrict__ deg, int E) {
    int e = blockIdx.x * blockDim.x + threadIdx.x;
    if (e < E) atomicAdd(&deg[dst[e]], 1);
}

__global__ void dinv_kernel(const int* __restrict__ deg, float* __restrict__ dinv, int N) {
    int v = blockIdx.x * blockDim.x + threadIdx.x;
    if (v < N) dinv[v] = rsqrtf((float)(deg[v] + 1));
}

// ---------- xs build (XCD-sharded layout) + dinv, fused ----------
// shard g holds cols [g*16, g*16+16): xs[((g*N + node)*16) + (col&15)]
__global__ void xs_kernel(const float* __restrict__ x, const int* __restrict__ deg,
                          float* __restrict__ dinv, unsigned short* __restrict__ xs,
                          int N, int total4) {
    int i = blockIdx.x * blockDim.x + threadIdx.x;
    if (i >= total4) return;
    int node = i >> 5, q = i & 31;
    float dv = rsqrtf((float)(deg[node] + 1));
    if (q == 0) dinv[node] = dv;
    float4 f = ((const float4*)x)[i];
    ushort4 o;
    o.x = f2bf(dv * f.x); o.y = f2bf(dv * f.y);
    o.z = f2bf(dv * f.z); o.w = f2bf(dv * f.w);
    int g = q >> 2, w = (q & 3) * 4;
    *(ushort4*)&xs[((size_t)g * N + node) * 16 + w] = o;
}

// ---------- Wt = bf16(W^T); fused BN affine ----------
__global__ void wt_kernel(const float* __restrict__ W, const float* __restrict__ b,
                          const float* __restrict__ gamma, const float* __restrict__ beta,
                          const float* __restrict__ mean, const float* __restrict__ var,
                          unsigned short* __restrict__ Wt, float* __restrict__ scv,
                          float* __restrict__ pov) {
    int t = blockIdx.x * blockDim.x + threadIdx.x;
    int k = t >> 7, n = t & 127;
    Wt[(size_t)n * D + k] = f2bf(W[t]);
    if (t < D) {
        float sc = gamma[t] * rsqrtf(var[t] + BN_EPS);
        scv[t] = sc;
        pov[t] = (b[t] - mean[t]) * sc + beta[t];
    }
}

// ---------- degree scan (3 wide phases) ----------
__global__ __launch_bounds__(256) void scan1_kernel(const int* __restrict__ deg,
                                                    int* __restrict__ bsum, int N) {
    __shared__ int s[256];
    int t = threadIdx.x;
    int v = blockIdx.x * 256 + t;
    s[t] = (v < N) ? deg[v] : 0;
    for (int st = 128; st > 0; st >>= 1) {
        __syncthreads();
        if (t < st) s[t] += s[t + st];
    }
    if (t == 0) bsum[blockIdx.x] = s[0];
}

__global__ __launch_bounds__(512) void scan2_kernel(int* __restrict__ bsum,
                                                    int* __restrict__ offs, int P, int N) {
    __shared__ int a[512];
    int t = threadIdx.x;
    int orig = (t < P) ? bsum[t] : 0;
    a[t] = orig;
    __syncthreads();
    for (int d = 1; d < 512; d <<= 1) {
        int tv = (t >= d) ? a[t - d] : 0;
        __syncthreads();
        a[t] += tv;
        __syncthreads();
    }
    if (t < P) bsum[t] = a[t] - orig;
    if (t == 0) offs[N] = a[511];
}

__global__ __launch_bounds__(256) void scan3_kernel(const int* __restrict__ deg,
                                                    const int* __restrict__ bsum,
                                                    int* __restrict__ offs,
                                                    int* __restrict__ cursor, int N) {
    __shared__ int a[256];
    int t = threadIdx.x;
    int v = blockIdx.x * 256 + t;
    int d = (v < N) ? deg[v] : 0;
    a[t] = d;
    __syncthreads();
    for (int st = 1; st < 256; st <<= 1) {
        int tv = (t >= st) ? a[t - st] : 0;
        __syncthreads();
        a[t] += tv;
        __syncthreads();
    }
    if (v < N) {
        int off = bsum[blockIdx.x] + a[t] - d;
        offs[v] = off;
        cursor[v] = off;
    }
}

// ---------- fine CSR fill from bucketed pairs ----------
__global__ __launch_bounds__(256) void pC_kernel(const int2* __restrict__ pairs,
                                                 int* __restrict__ cursor,
                                                 int* __restrict__ colidx, int E) {
    int base = blockIdx.x * CHC;
    int lim = min(CHC, E - base);
    for (int i = threadIdx.x; i < lim; i += 256) {
        int2 p = pairs[base + i];
        int pos = atomicAdd(&cursor[p.y], 1);
        colidx[pos] = p.x;
    }
}

// ---------- fallback CSR fill ----------
__global__ void fill_kernel(const int* __restrict__ src, const int* __restrict__ dst,
                            int* __restrict__ cursor, int* __restrict__ colidx, int E) {
    int e = blockIdx.x * blockDim.x + threadIdx.x;
    if (e < E) {
        int d = dst[e];
        int pos = atomicAdd(&cursor[d], 1);
        colidx[pos] = src[e];
    }
}

// ---------- gather-aggregate ----------
// Fast path: shard = blockIdx&7 (XCD-resident 3.2MB slice). Wave lanes =
// (edge-slot e = lane>>3) x (dword d = lane&7); 8 edges x 32B per iter;
// shuffle-xor reduce over e. colidx/offs read non-temporally.
__global__ __launch_bounds__(256) void agg_kernel(
    const float* __restrict__ x, const unsigned short* __restrict__ xs,
    const float* __restrict__ dinv, const int* __restrict__ offs,
    const int* __restrict__ colidx, float* __restrict__ outp,
    unsigned int* __restrict__ aggb, int N, int E) {
    if (xs) {
        int g = blockIdx.x & 7;
        const unsigned int* shard = (const unsigned int*)xs + (size_t)g * N * 8;
        unsigned int* aggs = aggb + (size_t)g * N * 8;
        int lane = threadIdx.x & 63;
        int e = lane >> 3, d = lane & 7;
        int node0 = ((blockIdx.x >> 3) * 4 + (threadIdx.x >> 6)) * 8;
#pragma unroll 1
        for (int t = 0; t < 8; ++t) {
            int v = node0 + t;
            if (v >= N) break;
            int p = __builtin_nontemporal_load(offs + v);
            int pe = __builtin_nontemporal_load(offs + v + 1);
            float dv = dinv[v];
            unsigned int sv = shard[(size_t)v * 8 + d];  // self row (broadcast)
            float a0 = (e == 0) ? bf2f((unsigned short)sv) : 0.f;
            float a1 = (e == 0) ? bf2f((unsigned short)(sv >> 16)) : 0.f;
            for (int base = p; base < pe; base += 8) {
                int ee = base + e;
                bool act = ee < pe;
                int ce = __builtin_nontemporal_load(colidx + (ee < E ? ee : E - 1));
                int idx = act ? ce : v;
                unsigned int val = shard[(size_t)idx * 8 + d];
                float m = act ? 1.f : 0.f;
                a0 = fmaf(m, bf2f((unsigned short)val), a0);
                a1 = fmaf(m, bf2f((unsigned short)(val >> 16)), a1);
            }
            a0 += __shfl_xor(a0, 8);  a1 += __shfl_xor(a1, 8);
            a0 += __shfl_xor(a0, 16); a1 += __shfl_xor(a1, 16);
            a0 += __shfl_xor(a0, 32); a1 += __shfl_xor(a1, 32);
            if (e == 0) {
                unsigned int o = (unsigned int)f2bf(dv * a0) |
                                 ((unsigned int)f2bf(dv * a1) << 16);
                aggs[(size_t)v * 8 + d] = o;
            }
        }
    } else {
        // fallback: one wave per node, fp32, row-major out
        int wid = (blockIdx.x * blockDim.x + threadIdx.x) >> 6;
        if (wid >= N) return;
        int lane = threadIdx.x & 63;
        float dv = dinv[wid];
        const float2* x2 = (const float2*)x;
        float2 s = x2[(size_t)wid * 64 + lane];
        float a0 = dv * s.x, a1 = dv * s.y;
        int p = offs[wid], pe = offs[wid + 1];
        for (; p < pe; ++p) {
            int u = colidx[p];
            float du = dinv[u];
            float2 vv = x2[(size_t)u * 64 + lane];
            a0 += du * vv.x;
            a1 += du * vv.y;
        }
        float2 r;
        r.x = dv * a0;
        r.y = dv * a1;
        ((float2*)outp)[(size_t)wid * 64 + lane] = r;
    }
}

// ---------- MFMA GEMM: out = relu(BN(agg @ W + b)) + x ----------
__global__ __launch_bounds__(256) void gemm_kernel(
    float* __restrict__ outp, const float* __restrict__ xg,
    const unsigned short* __restrict__ Wt, const unsigned short* __restrict__ aggb,
    const float* __restrict__ scv, const float* __restrict__ pov, int nTiles, int N) {
    int wid = (blockIdx.x * blockDim.x + threadIdx.x) >> 6;
    if (wid >= nTiles) return;
    int lane = threadIdx.x & 63;
    int m = lane & 15, quad = lane >> 4;
    int row0 = wid * 16;

    short8 B[8][4];
#pragma unroll
    for (int cg = 0; cg < 8; ++cg)
#pragma unroll
        for (int ks = 0; ks < 4; ++ks)
            B[cg][ks] = *(const short8*)&Wt[(size_t)(cg * 16 + m) * D + ks * 32 + quad * 8];

    short8 A[4];
    if (aggb) {
        // sharded layout: col run [cb, cb+8) lives in shard cb>>4 at offset cb&15
#pragma unroll
        for (int ks = 0; ks < 4; ++ks) {
            int cb = ks * 32 + quad * 8;
            A[ks] = *(const short8*)&aggb[((size_t)(cb >> 4) * N + row0 + m) * 16 + (cb & 15)];
        }
    } else {
        const float* arow = outp + (size_t)(row0 + m) * D;
#pragma unroll
        for (int ks = 0; ks < 4; ++ks) {
            float4 f0 = *(const float4*)(arow + ks * 32 + quad * 8);
            float4 f1 = *(const float4*)(arow + ks * 32 + quad * 8 + 4);
            short8 af;
            af[0] = (short)f2bf(f0.x); af[1] = (short)f2bf(f0.y);
            af[2] = (short)f2bf(f0.z); af[3] = (short)f2bf(f0.w);
            af[4] = (short)f2bf(f1.x); af[5] = (short)f2bf(f1.y);
            af[6] = (short)f2bf(f1.z); af[7] = (short)f2bf(f1.w);
            A[ks] = af;
        }
    }

#pragma unroll
    for (int cg = 0; cg < 8; ++cg) {
        floatx4 acc = {0.f, 0.f, 0.f, 0.f};
#pragma unroll
        for (int ks = 0; ks < 4; ++ks)
            acc = __builtin_amdgcn_mfma_f32_16x16x32_bf16(A[ks], B[cg][ks], acc, 0, 0, 0);
        int col = cg * 16 + m;
        float sc = scv[col], po = pov[col];
#pragma unroll
        for (int i = 0; i < 4; ++i) {
            int row = row0 + quad * 4 + i;
            float bn = acc[i] * sc + po;
            size_t idx = (size_t)row * D + col;
            outp[idx] = fmaxf(bn, 0.f) + xg[idx];
        }
    }
}

extern "C" void kernel_launch(void* const* d_in, const int* in_sizes, int n_in,
                              void* d_out, int out_size, void* d_ws, size_t ws_size,
                              hipStream_t stream) {
    const float* x = (const float*)d_in[0];
    const int* edge = (const int*)d_in[1];
    const float* Wm = (const float*)d_in[2];
    const float* b = (const float*)d_in[3];
    const float* gamma = (const float*)d_in[4];
    const float* beta = (const float*)d_in[5];
    const float* mean = (const float*)d_in[6];
    const float* var = (const float*)d_in[7];
    float* out = (float*)d_out;

    int N = in_sizes[0] / D;
    int E = in_sizes[1] / 2;
    const int* src = edge;
    const int* dst = edge + E;
    int P = (N + 255) / 256;

    // ---- workspace layout ----
    char* w = (char*)d_ws;
    size_t cur = 0;
    auto take = [&](size_t bytes) -> void* {
        cur = (cur + 15) & ~(size_t)15;
        void* p = w + cur;
        cur += bytes;
        return p;
    };
    int* deg = (int*)take((size_t)N * 4);
    int* bucketTot = (int*)take(NBUCK * 4);
    int* bucketCur = (int*)take(NBUCK * 4);
    float* dinv = (float*)take((size_t)N * 4);
    int* offs = (int*)take((size_t)(N + 1) * 4);
    int* cursor = (int*)take((size_t)N * 4);
    int* bsum = (int*)take((size_t)(P + 1) * 4);
    unsigned short* Wt = (unsigned short*)take((size_t)D * D * 2);
    float* scv = (float*)take(D * 4);
    float* pov = (float*)take(D * 4);
    int* colidx = (int*)take((size_t)E * 4);
    cur = (cur + 15) & ~(size_t)15;
    size_t fixedEnd = cur;

    size_t xsBytes = (size_t)N * D * 2;
    size_t zoneBytes = (xsBytes > (size_t)E * 8) ? xsBytes : (size_t)E * 8;
    bool fast = fixedEnd + xsBytes + zoneBytes <= ws_size;

    unsigned short* xs = nullptr;
    int2* pairs = nullptr;
    unsigned int* aggb = nullptr;
    if (fast) {
        xs = (unsigned short*)(w + fixedEnd);
        pairs = (int2*)(w + fixedEnd + xsBytes);       // dead after pC
        aggb = (unsigned int*)(w + fixedEnd + xsBytes); // aliases pairs
    }

    wt_kernel<<<(D * D) / 256, 256, 0, stream>>>(Wm, b, gamma, beta, mean, var, Wt, scv, pov);
    hipMemsetAsync(deg, 0, sizeof(int) * N, stream);
    hipMemsetAsync(bucketTot, 0, sizeof(int) * NBUCK, stream);

    if (fast) {
        pA_kernel<<<1024, 256, 0, stream>>>(dst, bucketTot, deg, E);
        tinyScan_kernel<<<1, NBUCK, 0, stream>>>(bucketTot, bucketCur);
        pB_kernel<<<(E + CHB - 1) / CHB, 256, 0, stream>>>(src, dst, bucketCur, pairs, E);
    } else {
        deg_kernel<<<(E + 255) / 256, 256, 0, stream>>>(dst, deg, E);
        dinv_kernel<<<(N + 255) / 256, 256, 0, stream>>>(deg, dinv, N);
    }
    scan1_kernel<<<P, 256, 0, stream>>>(deg, bsum, N);
    scan2_kernel<<<1, 512, 0, stream>>>(bsum, offs, P, N);
    scan3_kernel<<<P, 256, 0, stream>>>(deg, bsum, offs, cursor, N);
    if (fast) {
        xs_kernel<<<(N * 32 + 255) / 256, 256, 0, stream>>>(x, deg, dinv, xs, N, N * 32);
        pC_kernel<<<(E + CHC - 1) / CHC, 256, 0, stream>>>(pairs, cursor, colidx, E);
    } else {
        fill_kernel<<<(E + 255) / 256, 256, 0, stream>>>(src, dst, cursor, colidx, E);
    }
    // grids coincide: fast needs ceil(N/32)*8 blocks; fallback needs ceil(N*64/256)
    int aggBlocks = fast ? ((N + 31) / 32) * 8 : (N * 64 + 255) / 256;
    agg_kernel<<<aggBlocks, 256, 0, stream>>>(x, xs, dinv, offs, colidx, out, aggb, N, E);
    int nTiles = (N + 15) / 16;
    gemm_kernel<<<(nTiles * 64 + 255) / 256, 256, 0, stream>>>(
        out, x, Wt, (const unsigned short*)aggb, scv, pov, nTiles, N);
}

// Round 5
// 360.209 us; speedup vs baseline: 1.6292x; 1.6292x over previous
//
#include <hip/hip_runtime.h>

#define D 128
#define BN_EPS 1e-5f
#define NBUCK 256     // coarse buckets, dst>>9 (196 used at N=100K)
#define BSHIFT 9
#define CHB 4096      // edges per block, partition scatter
#define CHC 4096      // edges per block, fine fill

using short8 = __attribute__((ext_vector_type(8))) short;
using floatx4 = __attribute__((ext_vector_type(4))) float;

__device__ inline unsigned short f2bf(float f) {
    unsigned u = __float_as_uint(f);
    u += 0x7fff + ((u >> 16) & 1);  // RNE
    return (unsigned short)(u >> 16);
}
__device__ inline float bf2f(unsigned short s) {
    return __uint_as_float(((unsigned)s) << 16);
}

// ---------- pA: global bucket histogram only (LDS-aggregated) ----------
__global__ __launch_bounds__(256) void pA_kernel(const int* __restrict__ dst,
                                                 int* __restrict__ bucketTot, int E) {
    __shared__ int lh[NBUCK];
    int tid = threadIdx.x;
    lh[tid] = 0;
    __syncthreads();
    for (int i = blockIdx.x * 256 + tid; i < E; i += gridDim.x * 256)
        atomicAdd(&lh[dst[i] >> BSHIFT], 1);
    __syncthreads();
    if (lh[tid]) atomicAdd(&bucketTot[tid], lh[tid]);
}

// ---------- tiny scan: bucketTot -> bucketCur (exclusive bases) ----------
__global__ __launch_bounds__(256) void tinyScan_kernel(const int* __restrict__ bucketTot,
                                                       int* __restrict__ bucketCur) {
    __shared__ int a[NBUCK];
    int t = threadIdx.x;
    int orig = bucketTot[t];
    a[t] = orig;
    __syncthreads();
    for (int d = 1; d < NBUCK; d <<= 1) {
        int v = (t >= d) ? a[t - d] : 0;
        __syncthreads();
        a[t] += v;
        __syncthreads();
    }
    bucketCur[t] = a[t] - orig;  // exclusive
}

// ---------- pB: reservation-based partition into bucket order ----------
__global__ __launch_bounds__(256) void pB_kernel(const int* __restrict__ src,
                                                 const int* __restrict__ dst,
                                                 int* __restrict__ bucketCur,
                                                 int2* __restrict__ pairs, int E) {
    __shared__ int2 se[CHB];
    __shared__ int lh[NBUCK];
    __shared__ int lcur[NBUCK];
    int tid = threadIdx.x;
    lh[tid] = 0;
    __syncthreads();
    int base = blockIdx.x * CHB;
    int lim = min(CHB, E - base);
    for (int i = tid; i < lim; i += 256) {
        int s = src[base + i], d = dst[base + i];
        se[i] = make_int2(s, d);
        atomicAdd(&lh[d >> BSHIFT], 1);
    }
    __syncthreads();
    int c = lh[tid];
    lcur[tid] = c ? atomicAdd(&bucketCur[tid], c) : 0;
    __syncthreads();
    for (int i = tid; i < lim; i += 256) {
        int2 p = se[i];
        int pos = atomicAdd(&lcur[p.y >> BSHIFT], 1);
        pairs[pos] = p;
    }
}

// ---------- degree from bucketed pairs (localized atomics) ----------
__global__ void deg2_kernel(const int2* __restrict__ pairs, int* __restrict__ deg, int E) {
    int e = blockIdx.x * blockDim.x + threadIdx.x;
    if (e < E) atomicAdd(&deg[pairs[e].y], 1);
}

// ---------- fallback degree (random atomics) ----------
__global__ void deg_kernel(const int* __restrict__ dst, int* __restrict__ deg, int E) {
    int e = blockIdx.x * blockDim.x + threadIdx.x;
    if (e < E) atomicAdd(&deg[dst[e]], 1);
}

__global__ void dinv_kernel(const int* __restrict__ deg, float* __restrict__ dinv, int N) {
    int v = blockIdx.x * blockDim.x + threadIdx.x;
    if (v < N) dinv[v] = rsqrtf((float)(deg[v] + 1));
}

// ---------- xs build (row-major bf16) + dinv, fused ----------
__global__ void xs_kernel(const float* __restrict__ x, const int* __restrict__ deg,
                          float* __restrict__ dinv, unsigned short* __restrict__ xs,
                          int total4) {
    int i = blockIdx.x * blockDim.x + threadIdx.x;  // float4 index
    if (i >= total4) return;
    int node = i >> 5, q = i & 31;
    float dv = rsqrtf((float)(deg[node] + 1));
    if (q == 0) dinv[node] = dv;
    float4 f = ((const float4*)x)[i];
    ushort4 o;
    o.x = f2bf(dv * f.x); o.y = f2bf(dv * f.y);
    o.z = f2bf(dv * f.z); o.w = f2bf(dv * f.w);
    ((ushort4*)xs)[i] = o;
}

// ---------- Wt = bf16(W^T); fused BN affine ----------
__global__ void wt_kernel(const float* __restrict__ W, const float* __restrict__ b,
                          const float* __restrict__ gamma, const float* __restrict__ beta,
                          const float* __restrict__ mean, const float* __restrict__ var,
                          unsigned short* __restrict__ Wt, float* __restrict__ scv,
                          float* __restrict__ pov) {
    int t = blockIdx.x * blockDim.x + threadIdx.x;
    int k = t >> 7, n = t & 127;
    Wt[(size_t)n * D + k] = f2bf(W[t]);
    if (t < D) {
        float sc = gamma[t] * rsqrtf(var[t] + BN_EPS);
        scv[t] = sc;
        pov[t] = (b[t] - mean[t]) * sc + beta[t];
    }
}

// ---------- degree scan (3 wide phases) ----------
__global__ __launch_bounds__(256) void scan1_kernel(const int* __restrict__ deg,
                                                    int* __restrict__ bsum, int N) {
    __shared__ int s[256];
    int t = threadIdx.x;
    int v = blockIdx.x * 256 + t;
    s[t] = (v < N) ? deg[v] : 0;
    for (int st = 128; st > 0; st >>= 1) {
        __syncthreads();
        if (t < st) s[t] += s[t + st];
    }
    if (t == 0) bsum[blockIdx.x] = s[0];
}

__global__ __launch_bounds__(512) void scan2_kernel(int* __restrict__ bsum,
                                                    int* __restrict__ offs, int P, int N) {
    __shared__ int a[512];
    int t = threadIdx.x;
    int orig = (t < P) ? bsum[t] : 0;
    a[t] = orig;
    __syncthreads();
    for (int d = 1; d < 512; d <<= 1) {
        int tv = (t >= d) ? a[t - d] : 0;
        __syncthreads();
        a[t] += tv;
        __syncthreads();
    }
    if (t < P) bsum[t] = a[t] - orig;
    if (t == 0) offs[N] = a[511];
}

__global__ __launch_bounds__(256) void scan3_kernel(const int* __restrict__ deg,
                                                    const int* __restrict__ bsum,
                                                    int* __restrict__ offs,
                                                    int* __restrict__ cursor, int N) {
    __shared__ int a[256];
    int t = threadIdx.x;
    int v = blockIdx.x * 256 + t;
    int d = (v < N) ? deg[v] : 0;
    a[t] = d;
    __syncthreads();
    for (int st = 1; st < 256; st <<= 1) {
        int tv = (t >= st) ? a[t - st] : 0;
        __syncthreads();
        a[t] += tv;
        __syncthreads();
    }
    if (v < N) {
        int off = bsum[blockIdx.x] + a[t] - d;
        offs[v] = off;
        cursor[v] = off;
    }
}

// ---------- fine CSR fill from bucketed pairs ----------
__global__ __launch_bounds__(256) void pC_kernel(const int2* __restrict__ pairs,
                                                 int* __restrict__ cursor,
                                                 int* __restrict__ colidx, int E) {
    int base = blockIdx.x * CHC;
    int lim = min(CHC, E - base);
    for (int i = threadIdx.x; i < lim; i += 256) {
        int2 p = pairs[base + i];
        int pos = atomicAdd(&cursor[p.y], 1);
        colidx[pos] = p.x;
    }
}

// ---------- fallback CSR fill ----------
__global__ void fill_kernel(const int* __restrict__ src, const int* __restrict__ dst,
                            int* __restrict__ cursor, int* __restrict__ colidx, int E) {
    int e = blockIdx.x * blockDim.x + threadIdx.x;
    if (e < E) {
        int d = dst[e];
        int pos = atomicAdd(&cursor[d], 1);
        colidx[pos] = src[e];
    }
}

// ---------- gather-aggregate: one wave/node, lane = 2 packed cols ----------
// Full-row 256B gathers, 16 independent loads in flight (latency-tolerant shape).
__global__ __launch_bounds__(256) void agg_kernel(
    const float* __restrict__ x, const unsigned short* __restrict__ xs,
    const float* __restrict__ dinv, const int* __restrict__ offs,
    const int* __restrict__ colidx, float* __restrict__ outp,
    unsigned int* __restrict__ aggb, int N) {
    int wid = (blockIdx.x * blockDim.x + threadIdx.x) >> 6;
    if (wid >= N) return;
    int lane = threadIdx.x & 63;
    float dv = dinv[wid];
    float a0, a1;
    int p = offs[wid], pe = offs[wid + 1];
    if (xs) {
        const unsigned int* xs32 = (const unsigned int*)xs;
        unsigned int sv = xs32[(size_t)wid * 64 + lane];
        a0 = bf2f((unsigned short)sv);
        a1 = bf2f((unsigned short)(sv >> 16));
        for (; p + 16 <= pe; p += 16) {
            int u[16];
            unsigned int v[16];
#pragma unroll
            for (int j = 0; j < 16; ++j) u[j] = colidx[p + j];
#pragma unroll
            for (int j = 0; j < 16; ++j) v[j] = xs32[(size_t)u[j] * 64 + lane];
#pragma unroll
            for (int j = 0; j < 16; ++j) {
                a0 += bf2f((unsigned short)v[j]);
                a1 += bf2f((unsigned short)(v[j] >> 16));
            }
        }
        for (; p + 4 <= pe; p += 4) {
            int u[4];
            unsigned int v[4];
#pragma unroll
            for (int j = 0; j < 4; ++j) u[j] = colidx[p + j];
#pragma unroll
            for (int j = 0; j < 4; ++j) v[j] = xs32[(size_t)u[j] * 64 + lane];
#pragma unroll
            for (int j = 0; j < 4; ++j) {
                a0 += bf2f((unsigned short)v[j]);
                a1 += bf2f((unsigned short)(v[j] >> 16));
            }
        }
        for (; p < pe; ++p) {
            unsigned int v = xs32[(size_t)colidx[p] * 64 + lane];
            a0 += bf2f((unsigned short)v);
            a1 += bf2f((unsigned short)(v >> 16));
        }
        aggb[(size_t)wid * 64 + lane] =
            (unsigned int)f2bf(dv * a0) | ((unsigned int)f2bf(dv * a1) << 16);
    } else {
        const float2* x2 = (const float2*)x;
        float2 s = x2[(size_t)wid * 64 + lane];
        a0 = dv * s.x;
        a1 = dv * s.y;
        for (; p < pe; ++p) {
            int u = colidx[p];
            float du = dinv[u];
            float2 vv = x2[(size_t)u * 64 + lane];
            a0 += du * vv.x;
            a1 += du * vv.y;
        }
        float2 r;
        r.x = dv * a0;
        r.y = dv * a1;
        ((float2*)outp)[(size_t)wid * 64 + lane] = r;
    }
}

// ---------- MFMA GEMM: out = relu(BN(agg @ W + b)) + x ----------
__global__ __launch_bounds__(256) void gemm_kernel(
    float* __restrict__ outp, const float* __restrict__ xg,
    const unsigned short* __restrict__ Wt, const unsigned short* __restrict__ aggb,
    const float* __restrict__ scv, const float* __restrict__ pov, int nTiles) {
    int wid = (blockIdx.x * blockDim.x + threadIdx.x) >> 6;
    if (wid >= nTiles) return;
    int lane = threadIdx.x & 63;
    int m = lane & 15, quad = lane >> 4;
    int row0 = wid * 16;

    short8 B[8][4];
#pragma unroll
    for (int cg = 0; cg < 8; ++cg)
#pragma unroll
        for (int ks = 0; ks < 4; ++ks)
            B[cg][ks] = *(const short8*)&Wt[(size_t)(cg * 16 + m) * D + ks * 32 + quad * 8];

    short8 A[4];
    if (aggb) {
        const unsigned short* arow = aggb + (size_t)(row0 + m) * D;
#pragma unroll
        for (int ks = 0; ks < 4; ++ks)
            A[ks] = *(const short8*)&arow[ks * 32 + quad * 8];
    } else {
        const float* arow = outp + (size_t)(row0 + m) * D;
#pragma unroll
        for (int ks = 0; ks < 4; ++ks) {
            float4 f0 = *(const float4*)(arow + ks * 32 + quad * 8);
            float4 f1 = *(const float4*)(arow + ks * 32 + quad * 8 + 4);
            short8 af;
            af[0] = (short)f2bf(f0.x); af[1] = (short)f2bf(f0.y);
            af[2] = (short)f2bf(f0.z); af[3] = (short)f2bf(f0.w);
            af[4] = (short)f2bf(f1.x); af[5] = (short)f2bf(f1.y);
            af[6] = (short)f2bf(f1.z); af[7] = (short)f2bf(f1.w);
            A[ks] = af;
        }
    }

#pragma unroll
    for (int cg = 0; cg < 8; ++cg) {
        floatx4 acc = {0.f, 0.f, 0.f, 0.f};
#pragma unroll
        for (int ks = 0; ks < 4; ++ks)
            acc = __builtin_amdgcn_mfma_f32_16x16x32_bf16(A[ks], B[cg][ks], acc, 0, 0, 0);
        int col = cg * 16 + m;
        float sc = scv[col], po = pov[col];
#pragma unroll
        for (int i = 0; i < 4; ++i) {
            int row = row0 + quad * 4 + i;
            float bn = acc[i] * sc + po;
            size_t idx = (size_t)row * D + col;
            outp[idx] = fmaxf(bn, 0.f) + xg[idx];
        }
    }
}

extern "C" void kernel_launch(void* const* d_in, const int* in_sizes, int n_in,
                              void* d_out, int out_size, void* d_ws, size_t ws_size,
                              hipStream_t stream) {
    const float* x = (const float*)d_in[0];
    const int* edge = (const int*)d_in[1];
    const float* Wm = (const float*)d_in[2];
    const float* b = (const float*)d_in[3];
    const float* gamma = (const float*)d_in[4];
    const float* beta = (const float*)d_in[5];
    const float* mean = (const float*)d_in[6];
    const float* var = (const float*)d_in[7];
    float* out = (float*)d_out;

    int N = in_sizes[0] / D;
    int E = in_sizes[1] / 2;
    const int* src = edge;
    const int* dst = edge + E;
    int P = (N + 255) / 256;

    // ---- workspace layout ----
    char* w = (char*)d_ws;
    size_t cur = 0;
    auto take = [&](size_t bytes) -> void* {
        cur = (cur + 15) & ~(size_t)15;
        void* p = w + cur;
        cur += bytes;
        return p;
    };
    int* deg = (int*)take((size_t)N * 4);
    int* bucketTot = (int*)take(NBUCK * 4);
    int* bucketCur = (int*)take(NBUCK * 4);
    float* dinv = (float*)take((size_t)N * 4);
    int* offs = (int*)take((size_t)(N + 1) * 4);
    int* cursor = (int*)take((size_t)N * 4);
    int* bsum = (int*)take((size_t)(P + 1) * 4);
    unsigned short* Wt = (unsigned short*)take((size_t)D * D * 2);
    float* scv = (float*)take(D * 4);
    float* pov = (float*)take(D * 4);
    int* colidx = (int*)take((size_t)E * 4);
    cur = (cur + 15) & ~(size_t)15;
    size_t fixedEnd = cur;

    size_t xsBytes = (size_t)N * D * 2;
    size_t zoneBytes = (xsBytes > (size_t)E * 8) ? xsBytes : (size_t)E * 8;
    bool fast = fixedEnd + xsBytes + zoneBytes <= ws_size;

    unsigned short* xs = nullptr;
    int2* pairs = nullptr;
    unsigned int* aggb = nullptr;
    if (fast) {
        xs = (unsigned short*)(w + fixedEnd);
        pairs = (int2*)(w + fixedEnd + xsBytes);        // dead after pC
        aggb = (unsigned int*)(w + fixedEnd + xsBytes); // aliases pairs
    }

    wt_kernel<<<(D * D) / 256, 256, 0, stream>>>(Wm, b, gamma, beta, mean, var, Wt, scv, pov);
    hipMemsetAsync(deg, 0, sizeof(int) * N, stream);
    hipMemsetAsync(bucketTot, 0, sizeof(int) * NBUCK, stream);

    if (fast) {
        pA_kernel<<<1024, 256, 0, stream>>>(dst, bucketTot, E);
        tinyScan_kernel<<<1, NBUCK, 0, stream>>>(bucketTot, bucketCur);
        pB_kernel<<<(E + CHB - 1) / CHB, 256, 0, stream>>>(src, dst, bucketCur, pairs, E);
        deg2_kernel<<<(E + 255) / 256, 256, 0, stream>>>(pairs, deg, E);
        xs_kernel<<<(N * 32 + 255) / 256, 256, 0, stream>>>(x, deg, dinv, xs, N * 32);
    } else {
        deg_kernel<<<(E + 255) / 256, 256, 0, stream>>>(dst, deg, E);
        dinv_kernel<<<(N + 255) / 256, 256, 0, stream>>>(deg, dinv, N);
    }
    scan1_kernel<<<P, 256, 0, stream>>>(deg, bsum, N);
    scan2_kernel<<<1, 512, 0, stream>>>(bsum, offs, P, N);
    scan3_kernel<<<P, 256, 0, stream>>>(deg, bsum, offs, cursor, N);
    if (fast) {
        pC_kernel<<<(E + CHC - 1) / CHC, 256, 0, stream>>>(pairs, cursor, colidx, E);
    } else {
        fill_kernel<<<(E + 255) / 256, 256, 0, stream>>>(src, dst, cursor, colidx, E);
    }
    agg_kernel<<<(N * 64 + 255) / 256, 256, 0, stream>>>(x, xs, dinv, offs, colidx, out, aggb, N);
    int nTiles = (N + 15) / 16;
    gemm_kernel<<<(nTiles * 64 + 255) / 256, 256, 0, stream>>>(
        out, x, Wt, (const unsigned short*)aggb, scv, pov, nTiles);
}

// Round 6
// 294.723 us; speedup vs baseline: 1.9913x; 1.2222x over previous
//
#include <hip/hip_runtime.h>

#define D 128
#define BN_EPS 1e-5f
#define NBUCK 256     // coarse buckets, dst>>9 (196 used at N=100K)
#define BSHIFT 9

using short8 = __attribute__((ext_vector_type(8))) short;
using floatx4 = __attribute__((ext_vector_type(4))) float;

__device__ inline unsigned short f2bf(float f) {
    unsigned u = __float_as_uint(f);
    u += 0x7fff + ((u >> 16) & 1);  // RNE
    return (unsigned short)(u >> 16);
}
__device__ inline float bf2f(unsigned short s) {
    return __uint_as_float(((unsigned)s) << 16);
}

// ---------- wt: Wt = bf16(W^T), BN affine; block 0 zeroes counters ----------
__global__ void wt_kernel(const float* __restrict__ W, const float* __restrict__ b,
                          const float* __restrict__ gamma, const float* __restrict__ beta,
                          const float* __restrict__ mean, const float* __restrict__ var,
                          unsigned short* __restrict__ Wt, float* __restrict__ scv,
                          float* __restrict__ pov, int* __restrict__ bucketTot,
                          int* __restrict__ resCnt) {
    int t = blockIdx.x * blockDim.x + threadIdx.x;
    int k = t >> 7, n = t & 127;
    Wt[(size_t)n * D + k] = f2bf(W[t]);
    if (t < D) {
        float sc = gamma[t] * rsqrtf(var[t] + BN_EPS);
        scv[t] = sc;
        pov[t] = (b[t] - mean[t]) * sc + beta[t];
    }
    if (blockIdx.x == 0 && threadIdx.x < NBUCK) {
        bucketTot[threadIdx.x] = 0;
        resCnt[threadIdx.x] = 0;
    }
}

// ---------- pA: global bucket histogram (LDS-aggregated) ----------
__global__ __launch_bounds__(256) void pA_kernel(const int* __restrict__ dst,
                                                 int* __restrict__ bucketTot, int E) {
    __shared__ int lh[NBUCK];
    int tid = threadIdx.x;
    lh[tid] = 0;
    __syncthreads();
    for (int i = blockIdx.x * 256 + tid; i < E; i += gridDim.x * 256)
        atomicAdd(&lh[dst[i] >> BSHIFT], 1);
    __syncthreads();
    if (lh[tid]) atomicAdd(&bucketTot[tid], lh[tid]);
}

// ---------- pB: partition into bucket order (self-scanned bases) ----------
__global__ __launch_bounds__(256) void pB_kernel(const int* __restrict__ src,
                                                 const int* __restrict__ dst,
                                                 const int* __restrict__ bucketTot,
                                                 int* __restrict__ resCnt,
                                                 int2* __restrict__ pairs, int E) {
    __shared__ int sb[NBUCK];
    __shared__ int lh[NBUCK];
    __shared__ int lcur[NBUCK];
    int tid = threadIdx.x;
    sb[tid] = bucketTot[tid];
    lh[tid] = 0;
    __syncthreads();
    for (int d = 1; d < NBUCK; d <<= 1) {
        int v = (tid >= d) ? sb[tid - d] : 0;
        __syncthreads();
        sb[tid] += v;
        __syncthreads();
    }
    // sb = inclusive scan; exclusive base for bucket t = sb[t] - bucketTot[t]
    int chunk = (E + gridDim.x - 1) / gridDim.x;
    int base = blockIdx.x * chunk;
    int lim = min(chunk, E - base);
    if (lim <= 0) return;
    for (int i = tid; i < lim; i += 256) atomicAdd(&lh[dst[base + i] >> BSHIFT], 1);
    __syncthreads();
    int c = lh[tid];
    lcur[tid] = c ? (sb[tid] - bucketTot[tid]) + atomicAdd(&resCnt[tid], c) : 0;
    __syncthreads();
    for (int i = tid; i < lim; i += 256) {
        int s = src[base + i], d2 = dst[base + i];
        int pos = atomicAdd(&lcur[d2 >> BSHIFT], 1);
        pairs[pos] = make_int2(s, d2);
    }
}

// ---------- sort: within-bucket counting sort -> deg, offs, colidx ----------
// One block per bucket (512 nodes). Produces deg/offs coalesced (no atomics)
// and colidx grouped by dst; all writes in the bucket's own ~32KB window.
__global__ __launch_bounds__(512) void sort_kernel(const int2* __restrict__ pairs,
                                                   const int* __restrict__ bucketTot,
                                                   int* __restrict__ deg,
                                                   int* __restrict__ offs,
                                                   int* __restrict__ colidx, int N, int E) {
    __shared__ int sb[NBUCK];
    __shared__ int lh[512];
    __shared__ int lcur[512];
    int tid = threadIdx.x;
    int b = blockIdx.x;
    if (tid < NBUCK) sb[tid] = bucketTot[tid];
    __syncthreads();
    for (int d = 1; d < NBUCK; d <<= 1) {
        int v = 0;
        if (tid < NBUCK && tid >= d) v = sb[tid - d];
        __syncthreads();
        if (tid < NBUCK) sb[tid] += v;
        __syncthreads();
    }
    int cnt = bucketTot[b];
    int base = sb[b] - cnt;  // exclusive bucket base
    lh[tid] = 0;
    __syncthreads();
    for (int i = tid; i < cnt; i += 512)
        atomicAdd(&lh[pairs[base + i].y & 511], 1);
    __syncthreads();
    int orig = lh[tid];
    for (int d = 1; d < 512; d <<= 1) {
        int v = (tid >= d) ? lh[tid - d] : 0;
        __syncthreads();
        lh[tid] += v;
        __syncthreads();
    }
    int exc = lh[tid] - orig;
    int node = b * 512 + tid;
    if (node < N) {
        deg[node] = orig;
        offs[node] = base + exc;
    }
    lcur[tid] = exc;
    if (b == 0 && tid == 0) offs[N] = E;
    __syncthreads();
    for (int i = tid; i < cnt; i += 512) {
        int2 p = pairs[base + i];
        int pos = atomicAdd(&lcur[p.y & 511], 1);
        colidx[base + pos] = p.x;
    }
}

// ---------- xs build (row-major bf16) + dinv, fused ----------
__global__ void xs_kernel(const float* __restrict__ x, const int* __restrict__ deg,
                          float* __restrict__ dinv, unsigned short* __restrict__ xs,
                          int total4) {
    int i = blockIdx.x * blockDim.x + threadIdx.x;  // float4 index
    if (i >= total4) return;
    int node = i >> 5, q = i & 31;
    float dv = rsqrtf((float)(deg[node] + 1));
    if (q == 0) dinv[node] = dv;
    float4 f = ((const float4*)x)[i];
    ushort4 o;
    o.x = f2bf(dv * f.x); o.y = f2bf(dv * f.y);
    o.z = f2bf(dv * f.z); o.w = f2bf(dv * f.w);
    ((ushort4*)xs)[i] = o;
}

// ---------- fallback kernels (small-ws path) ----------
__global__ void deg_kernel(const int* __restrict__ dst, int* __restrict__ deg, int E) {
    int e = blockIdx.x * blockDim.x + threadIdx.x;
    if (e < E) atomicAdd(&deg[dst[e]], 1);
}

__global__ void dinv_kernel(const int* __restrict__ deg, float* __restrict__ dinv, int N) {
    int v = blockIdx.x * blockDim.x + threadIdx.x;
    if (v < N) dinv[v] = rsqrtf((float)(deg[v] + 1));
}

__global__ __launch_bounds__(256) void scan1_kernel(const int* __restrict__ deg,
                                                    int* __restrict__ bsum, int N) {
    __shared__ int s[256];
    int t = threadIdx.x;
    int v = blockIdx.x * 256 + t;
    s[t] = (v < N) ? deg[v] : 0;
    for (int st = 128; st > 0; st >>= 1) {
        __syncthreads();
        if (t < st) s[t] += s[t + st];
    }
    if (t == 0) bsum[blockIdx.x] = s[0];
}

__global__ __launch_bounds__(512) void scan2_kernel(int* __restrict__ bsum,
                                                    int* __restrict__ offs, int P, int N) {
    __shared__ int a[512];
    int t = threadIdx.x;
    int orig = (t < P) ? bsum[t] : 0;
    a[t] = orig;
    __syncthreads();
    for (int d = 1; d < 512; d <<= 1) {
        int tv = (t >= d) ? a[t - d] : 0;
        __syncthreads();
        a[t] += tv;
        __syncthreads();
    }
    if (t < P) bsum[t] = a[t] - orig;
    if (t == 0) offs[N] = a[511];
}

__global__ __launch_bounds__(256) void scan3_kernel(const int* __restrict__ deg,
                                                    const int* __restrict__ bsum,
                                                    int* __restrict__ offs,
                                                    int* __restrict__ cursor, int N) {
    __shared__ int a[256];
    int t = threadIdx.x;
    int v = blockIdx.x * 256 + t;
    int d = (v < N) ? deg[v] : 0;
    a[t] = d;
    __syncthreads();
    for (int st = 1; st < 256; st <<= 1) {
        int tv = (t >= st) ? a[t - st] : 0;
        __syncthreads();
        a[t] += tv;
        __syncthreads();
    }
    if (v < N) {
        int off = bsum[blockIdx.x] + a[t] - d;
        offs[v] = off;
        cursor[v] = off;
    }
}

__global__ void fill_kernel(const int* __restrict__ src, const int* __restrict__ dst,
                            int* __restrict__ cursor, int* __restrict__ colidx, int E) {
    int e = blockIdx.x * blockDim.x + threadIdx.x;
    if (e < E) {
        int d = dst[e];
        int pos = atomicAdd(&cursor[d], 1);
        colidx[pos] = src[e];
    }
}

// ---------- gather-aggregate: one wave/node, lane = 2 packed cols ----------
__global__ __launch_bounds__(256) void agg_kernel(
    const float* __restrict__ x, const unsigned short* __restrict__ xs,
    const float* __restrict__ dinv, const int* __restrict__ offs,
    const int* __restrict__ colidx, float* __restrict__ outp,
    unsigned int* __restrict__ aggb, int N) {
    int wid = (blockIdx.x * blockDim.x + threadIdx.x) >> 6;
    if (wid >= N) return;
    int lane = threadIdx.x & 63;
    float dv = dinv[wid];
    float a0, a1;
    int p = offs[wid], pe = offs[wid + 1];
    if (xs) {
        const unsigned int* xs32 = (const unsigned int*)xs;
        unsigned int sv = xs32[(size_t)wid * 64 + lane];
        a0 = bf2f((unsigned short)sv);
        a1 = bf2f((unsigned short)(sv >> 16));
        for (; p + 16 <= pe; p += 16) {
            int u[16];
            unsigned int v[16];
#pragma unroll
            for (int j = 0; j < 16; ++j) u[j] = colidx[p + j];
#pragma unroll
            for (int j = 0; j < 16; ++j) v[j] = xs32[(size_t)u[j] * 64 + lane];
#pragma unroll
            for (int j = 0; j < 16; ++j) {
                a0 += bf2f((unsigned short)v[j]);
                a1 += bf2f((unsigned short)(v[j] >> 16));
            }
        }
        for (; p + 4 <= pe; p += 4) {
            int u[4];
            unsigned int v[4];
#pragma unroll
            for (int j = 0; j < 4; ++j) u[j] = colidx[p + j];
#pragma unroll
            for (int j = 0; j < 4; ++j) v[j] = xs32[(size_t)u[j] * 64 + lane];
#pragma unroll
            for (int j = 0; j < 4; ++j) {
                a0 += bf2f((unsigned short)v[j]);
                a1 += bf2f((unsigned short)(v[j] >> 16));
            }
        }
        for (; p < pe; ++p) {
            unsigned int v = xs32[(size_t)colidx[p] * 64 + lane];
            a0 += bf2f((unsigned short)v);
            a1 += bf2f((unsigned short)(v >> 16));
        }
        aggb[(size_t)wid * 64 + lane] =
            (unsigned int)f2bf(dv * a0) | ((unsigned int)f2bf(dv * a1) << 16);
    } else {
        const float2* x2 = (const float2*)x;
        float2 s = x2[(size_t)wid * 64 + lane];
        a0 = dv * s.x;
        a1 = dv * s.y;
        for (; p < pe; ++p) {
            int u = colidx[p];
            float du = dinv[u];
            float2 vv = x2[(size_t)u * 64 + lane];
            a0 += du * vv.x;
            a1 += du * vv.y;
        }
        float2 r;
        r.x = dv * a0;
        r.y = dv * a1;
        ((float2*)outp)[(size_t)wid * 64 + lane] = r;
    }
}

// ---------- MFMA GEMM: out = relu(BN(agg @ W + b)) + x ----------
__global__ __launch_bounds__(256) void gemm_kernel(
    float* __restrict__ outp, const float* __restrict__ xg,
    const unsigned short* __restrict__ Wt, const unsigned short* __restrict__ aggb,
    const float* __restrict__ scv, const float* __restrict__ pov, int nTiles) {
    int wid = (blockIdx.x * blockDim.x + threadIdx.x) >> 6;
    if (wid >= nTiles) return;
    int lane = threadIdx.x & 63;
    int m = lane & 15, quad = lane >> 4;
    int row0 = wid * 16;

    short8 B[8][4];
#pragma unroll
    for (int cg = 0; cg < 8; ++cg)
#pragma unroll
        for (int ks = 0; ks < 4; ++ks)
            B[cg][ks] = *(const short8*)&Wt[(size_t)(cg * 16 + m) * D + ks * 32 + quad * 8];

    short8 A[4];
    if (aggb) {
        const unsigned short* arow = aggb + (size_t)(row0 + m) * D;
#pragma unroll
        for (int ks = 0; ks < 4; ++ks)
            A[ks] = *(const short8*)&arow[ks * 32 + quad * 8];
    } else {
        const float* arow = outp + (size_t)(row0 + m) * D;
#pragma unroll
        for (int ks = 0; ks < 4; ++ks) {
            float4 f0 = *(const float4*)(arow + ks * 32 + quad * 8);
            float4 f1 = *(const float4*)(arow + ks * 32 + quad * 8 + 4);
            short8 af;
            af[0] = (short)f2bf(f0.x); af[1] = (short)f2bf(f0.y);
            af[2] = (short)f2bf(f0.z); af[3] = (short)f2bf(f0.w);
            af[4] = (short)f2bf(f1.x); af[5] = (short)f2bf(f1.y);
            af[6] = (short)f2bf(f1.z); af[7] = (short)f2bf(f1.w);
            A[ks] = af;
        }
    }

#pragma unroll
    for (int cg = 0; cg < 8; ++cg) {
        floatx4 acc = {0.f, 0.f, 0.f, 0.f};
#pragma unroll
        for (int ks = 0; ks < 4; ++ks)
            acc = __builtin_amdgcn_mfma_f32_16x16x32_bf16(A[ks], B[cg][ks], acc, 0, 0, 0);
        int col = cg * 16 + m;
        float sc = scv[col], po = pov[col];
#pragma unroll
        for (int i = 0; i < 4; ++i) {
            int row = row0 + quad * 4 + i;
            float bn = acc[i] * sc + po;
            size_t idx = (size_t)row * D + col;
            outp[idx] = fmaxf(bn, 0.f) + xg[idx];
        }
    }
}

extern "C" void kernel_launch(void* const* d_in, const int* in_sizes, int n_in,
                              void* d_out, int out_size, void* d_ws, size_t ws_size,
                              hipStream_t stream) {
    const float* x = (const float*)d_in[0];
    const int* edge = (const int*)d_in[1];
    const float* Wm = (const float*)d_in[2];
    const float* b = (const float*)d_in[3];
    const float* gamma = (const float*)d_in[4];
    const float* beta = (const float*)d_in[5];
    const float* mean = (const float*)d_in[6];
    const float* var = (const float*)d_in[7];
    float* out = (float*)d_out;

    int N = in_sizes[0] / D;
    int E = in_sizes[1] / 2;
    const int* src = edge;
    const int* dst = edge + E;
    int P = (N + 255) / 256;

    // ---- workspace layout ----
    char* w = (char*)d_ws;
    size_t cur = 0;
    auto take = [&](size_t bytes) -> void* {
        cur = (cur + 15) & ~(size_t)15;
        void* p = w + cur;
        cur += bytes;
        return p;
    };
    int* deg = (int*)take((size_t)N * 4);
    int* bucketTot = (int*)take(NBUCK * 4);
    int* resCnt = (int*)take(NBUCK * 4);
    float* dinv = (float*)take((size_t)N * 4);
    int* offs = (int*)take((size_t)(N + 1) * 4);
    int* cursor = (int*)take((size_t)N * 4);
    int* bsum = (int*)take((size_t)(P + 1) * 4);
    unsigned short* Wt = (unsigned short*)take((size_t)D * D * 2);
    float* scv = (float*)take(D * 4);
    float* pov = (float*)take(D * 4);
    int* colidx = (int*)take((size_t)E * 4);
    cur = (cur + 15) & ~(size_t)15;
    size_t fixedEnd = cur;

    size_t xsBytes = (size_t)N * D * 2;
    size_t zoneBytes = (xsBytes > (size_t)E * 8) ? xsBytes : (size_t)E * 8;
    bool fast = fixedEnd + xsBytes + zoneBytes <= ws_size;

    unsigned short* xs = nullptr;
    int2* pairs = nullptr;
    unsigned int* aggb = nullptr;
    if (fast) {
        xs = (unsigned short*)(w + fixedEnd);
        pairs = (int2*)(w + fixedEnd + xsBytes);        // dead after sort_kernel
        aggb = (unsigned int*)(w + fixedEnd + xsBytes); // aliases pairs
    }

    wt_kernel<<<(D * D) / 256, 256, 0, stream>>>(Wm, b, gamma, beta, mean, var, Wt, scv,
                                                 pov, bucketTot, resCnt);

    if (fast) {
        pA_kernel<<<1024, 256, 0, stream>>>(dst, bucketTot, E);
        pB_kernel<<<256, 256, 0, stream>>>(src, dst, bucketTot, resCnt, pairs, E);
        sort_kernel<<<NBUCK, 512, 0, stream>>>(pairs, bucketTot, deg, offs, colidx, N, E);
        xs_kernel<<<(N * 32 + 255) / 256, 256, 0, stream>>>(x, deg, dinv, xs, N * 32);
    } else {
        hipMemsetAsync(deg, 0, sizeof(int) * N, stream);
        deg_kernel<<<(E + 255) / 256, 256, 0, stream>>>(dst, deg, E);
        dinv_kernel<<<(N + 255) / 256, 256, 0, stream>>>(deg, dinv, N);
        scan1_kernel<<<P, 256, 0, stream>>>(deg, bsum, N);
        scan2_kernel<<<1, 512, 0, stream>>>(bsum, offs, P, N);
        scan3_kernel<<<P, 256, 0, stream>>>(deg, bsum, offs, cursor, N);
        fill_kernel<<<(E + 255) / 256, 256, 0, stream>>>(src, dst, cursor, colidx, E);
    }
    agg_kernel<<<(N * 64 + 255) / 256, 256, 0, stream>>>(x, xs, dinv, offs, colidx, out, aggb, N);
    int nTiles = (N + 15) / 16;
    gemm_kernel<<<(nTiles * 64 + 255) / 256, 256, 0, stream>>>(
        out, x, Wt, (const unsigned short*)aggb, scv, pov, nTiles);
}